// Round 1
// baseline (3007.916 us; speedup 1.0000x reference)
//
#include <hip/hip_runtime.h>

// Problem constants (fixed by the reference)
constexpr int B = 32, S = 2048, D = 1024, N = 256;
constexpr int CHUNK  = 64;          // timesteps per pipeline chunk (= scan inner block)
constexpr int NCHUNK = S / CHUNK;   // 32 chunks
constexpr int WBLK   = 512;         // worker blocks (mean + out), 4 waves each = 2048 waves
constexpr int SBLK   = 8;           // scan blocks, 4 batch-waves each = 32 batches

#define DEV __device__ __forceinline__

// ---- DPP wave-64 reduction helpers -------------------------------------
template <int CTRL>
DEV float dpp_add(float x) {
  int y = __builtin_amdgcn_update_dpp(0, __float_as_int(x), CTRL, 0xF, 0xF, true);
  return x + __int_as_float(y);
}

DEV float rdlane(float v, int l) {
  return __int_as_float(__builtin_amdgcn_readlane(__float_as_int(v), l));
}

DEV void wave_reduce3(float& a, float& b, float& c) {
  a = dpp_add<0x111>(a); b = dpp_add<0x111>(b); c = dpp_add<0x111>(c);
  a = dpp_add<0x112>(a); b = dpp_add<0x112>(b); c = dpp_add<0x112>(c);
  a = dpp_add<0x114>(a); b = dpp_add<0x114>(b); c = dpp_add<0x114>(c);
  a = dpp_add<0x118>(a); b = dpp_add<0x118>(b); c = dpp_add<0x118>(c);
  a = dpp_add<0x142>(a); b = dpp_add<0x142>(b); c = dpp_add<0x142>(c);
  a = dpp_add<0x143>(a); b = dpp_add<0x143>(b); c = dpp_add<0x143>(c);
  a = rdlane(a, 63);
  b = rdlane(b, 63);
  c = rdlane(c, 63);
}

// ---- cross-XCD communication primitives --------------------------------
// Data is published with device-scope RMW (atomicExch -> coherent point).
// Flags are atomicAdd after an explicit vmcnt(0) drain.
// Consumers poll relaxed agent-scope atomic loads (sc0/sc1 -> bypass L1/L2),
// then __threadfence() as the acquire barrier before reading data.
DEV float ld_agent(const float* p) {
  return __hip_atomic_load(p, __ATOMIC_RELAXED, __HIP_MEMORY_SCOPE_AGENT);
}
DEV int ld_flag(const int* p) {
  return __hip_atomic_load(p, __ATOMIC_RELAXED, __HIP_MEMORY_SCOPE_AGENT);
}

// ---- fused pipeline kernel ---------------------------------------------
// blocks [0, WBLK): workers. Phase 1: mean of all chunks (chunk-major, so
// chunk 0 completes in ~1.3 us). Phase 2: out-stream chunk c once scan
// publishes s[:, c]. blocks [WBLK, WBLK+SBLK): 32 scan waves (1 per batch).
// __launch_bounds__(256,4) => >=4 blocks/CU co-resident => 1024 slots >= 520
// blocks: every block is resident, spin-waits cannot deadlock.
__global__ __launch_bounds__(256, 4) void fused(
    const float4* __restrict__ x4, const float* __restrict__ llr,
    const float* __restrict__ logb, const float* __restrict__ c,
    const float* __restrict__ lstep, const float* __restrict__ gma,
    const float* __restrict__ bta, const float* __restrict__ logd,
    const float* __restrict__ alpha, float* __restrict__ u,
    float* __restrict__ s, int* __restrict__ ucnt, int* __restrict__ scnt,
    float4* __restrict__ o4) {
  const int wv   = threadIdx.x >> 6;
  const int lane = threadIdx.x & 63;

  if (blockIdx.x < WBLK) {
    // =================== WORKER ===================
    const int wid = (blockIdx.x << 2) | wv;   // 0..2047 -> exactly 1 row/chunk
    const int b = wid >> 6, i = wid & 63;

    // ---- phase 1: mean (no waits; chunk-major so chunk 0 lands first) ----
    for (int ch = 0; ch < NCHUNK; ++ch) {
      const int t = (ch << 6) | i;
      const float4* xr = x4 + (size_t)(b * S + t) * (D / 4);
      float sm = 0.f;
#pragma unroll
      for (int k = 0; k < 4; ++k) {
        float4 v = xr[lane + (k << 6)];
        sm += (v.x + v.y) + (v.z + v.w);
      }
#pragma unroll
      for (int off = 32; off; off >>= 1) sm += __shfl_xor(sm, off, 64);
      if (lane == 0) atomicExch(&u[b * S + t], sm * (1.f / 1024.f));
      asm volatile("s_waitcnt vmcnt(0)" ::: "memory");  // u at coherent point
      __syncthreads();                                   // all 4 rows of block done
      if (threadIdx.x == 0) atomicAdd(&ucnt[ch], 1);     // fire-and-forget
    }

    // ---- phase 2: out, trailing the scan chunk-by-chunk ----
    const float asig = 1.f / (1.f + expf(-alpha[0]));
    const float dd   = expf(logd[0]);
    const float cx   = asig + (1.f - asig) * dd;
    const float cs   = 1.f - asig;
    for (int ch = 0; ch < NCHUNK; ++ch) {
      while (ld_flag(&scnt[ch]) < B) __builtin_amdgcn_s_sleep(16);
      __threadfence();                                   // acquire
      const int t = (ch << 6) | i;
      const float sv = cs * ld_agent(&s[b * S + t]);     // 1 bcast load / wave
      const float4* xr   = x4 + (size_t)(b * S + t) * (D / 4);
      float4*       orow = o4 + (size_t)(b * S + t) * (D / 4);
#pragma unroll
      for (int k = 0; k < 4; ++k) {
        float4 v = xr[lane + (k << 6)];
        float4 o;
        o.x = fmaf(cx, v.x, sv);
        o.y = fmaf(cx, v.y, sv);
        o.z = fmaf(cx, v.z, sv);
        o.w = fmaf(cx, v.w, sv);
        orow[lane + (k << 6)] = o;
      }
    }
  } else {
    // =================== SCAN (math identical to 690us version) ===========
    const int b = ((blockIdx.x - WBLK) << 2) | wv;       // batch 0..31
    const float stp = expf(lstep[0]);

    float ag[4], ab[4], bd[4], cg[4];
    float Gp = 0.f, BCp = 0.f, d0 = 0.f;
#pragma unroll
    for (int k = 0; k < 4; ++k) {
      const int n = (k << 6) | lane;
      const float lam = -expf(llr[n]);
      const float sl  = stp * lam;
      const float adisc = (2.f + sl) / (2.f - sl);
      const float bdisc = stp * (1.f + adisc) * expf(logb[n]) * 0.5f;
      const float g  = gma[n];
      const float be = bta[n];
      const float cc = c[n];
      ag[k] = adisc * g;
      ab[k] = adisc * be;
      bd[k] = bdisc;
      cg[k] = cc * g;
      Gp  += cg[k];
      BCp += cc * be;
    }
    wave_reduce3(Gp, BCp, d0);
    const float G = Gp, BC = BCp;
    const float Ceps = 65536.f * 1e-5f;

    const float* urow = u + b * S;
    float* srow = s + b * S;

    while (ld_flag(&ucnt[0]) < WBLK) __builtin_amdgcn_s_sleep(2);
    __threadfence();
    float uch = ld_agent(urow + lane);                   // chunk 0 of u
    const float u0 = rdlane(uch, 0);
    float z0 = bd[0] * u0, z1 = bd[1] * u0, z2 = bd[2] * u0, z3 = bd[3] * u0;

    for (int chn = 0; chn < NCHUNK; ++chn) {
      float uch_next = uch;                // chunk 31: value only feeds dead state
      if (chn < NCHUNK - 1) {
        while (ld_flag(&ucnt[chn + 1]) < WBLK) __builtin_amdgcn_s_sleep(2);
        __threadfence();
        uch_next = ld_agent(urow + ((chn + 1) << 6) + lane);  // hides under steps
      }
      float stk = 0.f;
#pragma unroll
      for (int tt = 0; tt < 64; ++tt) {
        float s1 = (z0 + z1) + (z2 + z3);
        float s2 = fmaf(z0, z0, z1 * z1) + fmaf(z2, z2, z3 * z3);
        float s3 = fmaf(z0, cg[0], z1 * cg[1]) + fmaf(z2, cg[2], z3 * cg[3]);
        wave_reduce3(s1, s2, s3);
        const float q = fmaf(256.f, s2, fmaf(-s1, s1, Ceps));
        const float r = __builtin_amdgcn_rsqf(q);        // v_rsq_f32
        const float st = fmaf(r, fmaf(256.f, s3, -s1 * G), BC);
        stk = (lane == tt) ? st : stk;

        const float un = (tt < 63) ? rdlane(uch, tt + 1) : rdlane(uch_next, 0);
        const float w0 = fmaf(256.f, z0, -s1);
        const float w1 = fmaf(256.f, z1, -s1);
        const float w2 = fmaf(256.f, z2, -s1);
        const float w3 = fmaf(256.f, z3, -s1);
        z0 = fmaf(ag[0] * w0, r, fmaf(bd[0], un, ab[0]));
        z1 = fmaf(ag[1] * w1, r, fmaf(bd[1], un, ab[1]));
        z2 = fmaf(ag[2] * w2, r, fmaf(bd[2], un, ab[2]));
        z3 = fmaf(ag[3] * w3, r, fmaf(bd[3], un, ab[3]));
      }
      atomicExch(&srow[(chn << 6) + lane], stk);          // publish s chunk
      asm volatile("s_waitcnt vmcnt(0)" ::: "memory");    // s at coherent point
      if (lane == 0) atomicAdd(&scnt[chn], 1);            // fire-and-forget
      uch = uch_next;
    }
  }
}

extern "C" void kernel_launch(void* const* d_in, const int* in_sizes, int n_in,
                              void* d_out, int out_size, void* d_ws, size_t ws_size,
                              hipStream_t stream) {
  const float* x     = (const float*)d_in[0];
  const float* llr   = (const float*)d_in[1];
  const float* logb  = (const float*)d_in[2];
  const float* c     = (const float*)d_in[3];
  const float* logd  = (const float*)d_in[4];
  const float* lstep = (const float*)d_in[5];
  const float* alpha = (const float*)d_in[6];
  const float* gma   = (const float*)d_in[7];
  const float* bta   = (const float*)d_in[8];

  float* u     = (float*)d_ws;            // B*S floats
  float* s     = u + B * S;               // B*S floats
  int*   flags = (int*)(s + B * S);       // ucnt[NCHUNK], scnt[NCHUNK]
  int*   ucnt  = flags;
  int*   scnt  = flags + NCHUNK;

  hipMemsetAsync(flags, 0, 2 * NCHUNK * sizeof(int), stream);
  fused<<<WBLK + SBLK, 256, 0, stream>>>(
      (const float4*)x, llr, logb, c, lstep, gma, bta, logd, alpha,
      u, s, ucnt, scnt, (float4*)d_out);
}

// Round 3
// 777.399 us; speedup vs baseline: 3.8692x; 3.8692x over previous
//
#include <hip/hip_runtime.h>

// Problem constants (fixed by the reference)
constexpr int B = 32, S = 2048, D = 1024, N = 256;
constexpr int NCHUNK = 32;          // S/64 pipeline chunks
constexpr int SBLK   = 4;           // scan blocks (first), 8 batch-waves each = 32
constexpr int WBLK   = 128;         // worker blocks, 8 waves x 2 rows = 16 rows/block
// Total 132 blocks <= 256 CUs: all blocks resident even at 1 block/CU.
// Flag dependency graph is acyclic: mean (no waits) -> uflag -> scan -> sflag -> out.

#define DEV __device__ __forceinline__

// ---- DPP wave-64 reduction helpers -------------------------------------
template <int CTRL>
DEV float dpp_add(float x) {
  int y = __builtin_amdgcn_update_dpp(0, __float_as_int(x), CTRL, 0xF, 0xF, true);
  return x + __int_as_float(y);
}

DEV float rdlane(float v, int l) {
  return __int_as_float(__builtin_amdgcn_readlane(__float_as_int(v), l));
}

DEV void wave_reduce3(float& a, float& b, float& c) {
  a = dpp_add<0x111>(a); b = dpp_add<0x111>(b); c = dpp_add<0x111>(c);
  a = dpp_add<0x112>(a); b = dpp_add<0x112>(b); c = dpp_add<0x112>(c);
  a = dpp_add<0x114>(a); b = dpp_add<0x114>(b); c = dpp_add<0x114>(c);
  a = dpp_add<0x118>(a); b = dpp_add<0x118>(b); c = dpp_add<0x118>(c);
  a = dpp_add<0x142>(a); b = dpp_add<0x142>(b); c = dpp_add<0x142>(c);
  a = dpp_add<0x143>(a); b = dpp_add<0x143>(b); c = dpp_add<0x143>(c);
  a = rdlane(a, 63);
  b = rdlane(b, 63);
  c = rdlane(c, 63);
}

// ---- cross-XCD communication primitives --------------------------------
// Data: atomicExch (device-scope RMW -> coherent point), vmcnt(0) drain,
// then flag RMW. Consumers: relaxed agent-scope atomic loads. This publish
// discipline is identical to the round-1 kernel that PASSED verification.
DEV float ld_agent(const float* p) {
  return __hip_atomic_load(p, __ATOMIC_RELAXED, __HIP_MEMORY_SCOPE_AGENT);
}
DEV int ld_flag(const int* p) {
  return __hip_atomic_load(p, __ATOMIC_RELAXED, __HIP_MEMORY_SCOPE_AGENT);
}

// ---- fused pipeline kernel ---------------------------------------------
// blocks [0, SBLK): scan, wave wv handles batch b = blockIdx*8+wv.
// blocks [SBLK, SBLK+WBLK): workers; block covers 16 consecutive rows of ONE
//   batch (b = wb/4); each wave owns 2 rows. Phase 1: mean, chunk-major.
//   Phase 2: out-stream chunk ch once scan publishes it.
// Flags (one 128B line per batch per array, ONE scalar poller per block):
//   uflag[b*32+ch]: worker blocks done with mean of (b,ch); ready at 4.
//   sflag[b*32]   : scan's monotonic chunk progress for batch b.
__global__ __launch_bounds__(512) void fused(
    const float4* __restrict__ x4, const float* __restrict__ llr,
    const float* __restrict__ logb, const float* __restrict__ c,
    const float* __restrict__ lstep, const float* __restrict__ gma,
    const float* __restrict__ bta, const float* __restrict__ logd,
    const float* __restrict__ alpha, float* __restrict__ u,
    float* __restrict__ s, int* __restrict__ uflag, int* __restrict__ sflag,
    float4* __restrict__ o4) {
  const int wv   = threadIdx.x >> 6;
  const int lane = threadIdx.x & 63;

  if (blockIdx.x >= SBLK) {
    // =================== WORKER ===================
    const int wb = blockIdx.x - SBLK;           // 0..127
    const int b  = wb >> 2;                     // 4 blocks per batch
    const int i0 = ((wb & 3) << 4) | (wv << 1); // rows (b,i0), (b,i0+1)

    // ---- phase 1: mean (no waits; chunk-major so chunk 0 lands first) ----
    for (int ch = 0; ch < NCHUNK; ++ch) {
      const int t0 = (ch << 6) | i0;
      const float4* xr = x4 + (size_t)(b * S + t0) * (D / 4);
      float s0 = 0.f, s1 = 0.f;
#pragma unroll
      for (int k = 0; k < 4; ++k) {
        float4 v0 = xr[lane + (k << 6)];
        float4 v1 = xr[(D / 4) + lane + (k << 6)];
        s0 += (v0.x + v0.y) + (v0.z + v0.w);
        s1 += (v1.x + v1.y) + (v1.z + v1.w);
      }
#pragma unroll
      for (int off = 32; off; off >>= 1) {
        s0 += __shfl_xor(s0, off, 64);
        s1 += __shfl_xor(s1, off, 64);
      }
      if (lane == 0) {
        atomicExch(&u[b * S + t0],     s0 * (1.f / 1024.f));
        atomicExch(&u[b * S + t0 + 1], s1 * (1.f / 1024.f));
      }
      asm volatile("s_waitcnt vmcnt(0)" ::: "memory");  // u at coherent point
      __syncthreads();                                  // all 16 rows done
      if (threadIdx.x == 0) atomicAdd(&uflag[(b << 5) + ch], 1);
    }

    // ---- phase 2: out, trailing the scan chunk-by-chunk ----
    const float asig = 1.f / (1.f + expf(-alpha[0]));
    const float dd   = expf(logd[0]);
    const float cx   = asig + (1.f - asig) * dd;
    const float cs   = 1.f - asig;
    for (int ch = 0; ch < NCHUNK; ++ch) {
      if (threadIdx.x == 0) {                    // ONE scalar poller per block
        while (ld_flag(&sflag[b << 5]) < ch + 1) __builtin_amdgcn_s_sleep(16);
      }
      __syncthreads();
      const int t0 = (ch << 6) | i0;
      float sv = (lane < 2) ? ld_agent(&s[b * S + t0 + lane]) : 0.f;
      const float sv0 = cs * rdlane(sv, 0);
      const float sv1 = cs * rdlane(sv, 1);
      const float4* xr   = x4 + (size_t)(b * S + t0) * (D / 4);
      float4*       orow = o4 + (size_t)(b * S + t0) * (D / 4);
#pragma unroll
      for (int k = 0; k < 4; ++k) {
        float4 v0 = xr[lane + (k << 6)];
        float4 v1 = xr[(D / 4) + lane + (k << 6)];
        float4 o0, o1;
        o0.x = fmaf(cx, v0.x, sv0); o0.y = fmaf(cx, v0.y, sv0);
        o0.z = fmaf(cx, v0.z, sv0); o0.w = fmaf(cx, v0.w, sv0);
        o1.x = fmaf(cx, v1.x, sv1); o1.y = fmaf(cx, v1.y, sv1);
        o1.z = fmaf(cx, v1.z, sv1); o1.w = fmaf(cx, v1.w, sv1);
        orow[lane + (k << 6)] = o0;
        orow[(D / 4) + lane + (k << 6)] = o1;
      }
    }
  } else {
    // =================== SCAN (math identical to 690us version) ===========
    const int b = (blockIdx.x << 3) | wv;             // batch 0..31
    const float stp = expf(lstep[0]);

    float ag[4], ab[4], bd[4], cg[4];
    float Gp = 0.f, BCp = 0.f, d0 = 0.f;
#pragma unroll
    for (int k = 0; k < 4; ++k) {
      const int n = (k << 6) | lane;
      const float lam = -expf(llr[n]);
      const float sl  = stp * lam;
      const float adisc = (2.f + sl) / (2.f - sl);
      const float bdisc = stp * (1.f + adisc) * expf(logb[n]) * 0.5f;
      const float g  = gma[n];
      const float be = bta[n];
      const float cc = c[n];
      ag[k] = adisc * g;
      ab[k] = adisc * be;
      bd[k] = bdisc;
      cg[k] = cc * g;
      Gp  += cg[k];
      BCp += cc * be;
    }
    wave_reduce3(Gp, BCp, d0);
    const float G = Gp, BC = BCp;
    const float Ceps = 65536.f * 1e-5f;

    const float* urow = u + b * S;
    float* srow = s + b * S;

    while (ld_flag(&uflag[b << 5]) < 4) __builtin_amdgcn_s_sleep(2);
    __threadfence();
    float uch = ld_agent(urow + lane);                // chunk 0 of u
    const float u0 = rdlane(uch, 0);
    float z0 = bd[0] * u0, z1 = bd[1] * u0, z2 = bd[2] * u0, z3 = bd[3] * u0;

    for (int chn = 0; chn < NCHUNK; ++chn) {
      float uch_next = uch;               // chunk 31: value only feeds dead state
      if (chn < NCHUNK - 1) {
        while (ld_flag(&uflag[(b << 5) + chn + 1]) < 4)
          __builtin_amdgcn_s_sleep(2);
        __threadfence();
        uch_next = ld_agent(urow + ((chn + 1) << 6) + lane);  // hides under steps
      }
      float stk = 0.f;
#pragma unroll
      for (int tt = 0; tt < 64; ++tt) {
        float s1 = (z0 + z1) + (z2 + z3);
        float s2 = fmaf(z0, z0, z1 * z1) + fmaf(z2, z2, z3 * z3);
        float s3 = fmaf(z0, cg[0], z1 * cg[1]) + fmaf(z2, cg[2], z3 * cg[3]);
        wave_reduce3(s1, s2, s3);
        const float q = fmaf(256.f, s2, fmaf(-s1, s1, Ceps));
        const float r = __builtin_amdgcn_rsqf(q);     // v_rsq_f32
        const float st = fmaf(r, fmaf(256.f, s3, -s1 * G), BC);
        stk = (lane == tt) ? st : stk;

        const float un = (tt < 63) ? rdlane(uch, tt + 1) : rdlane(uch_next, 0);
        const float w0 = fmaf(256.f, z0, -s1);
        const float w1 = fmaf(256.f, z1, -s1);
        const float w2 = fmaf(256.f, z2, -s1);
        const float w3 = fmaf(256.f, z3, -s1);
        z0 = fmaf(ag[0] * w0, r, fmaf(bd[0], un, ab[0]));
        z1 = fmaf(ag[1] * w1, r, fmaf(bd[1], un, ab[1]));
        z2 = fmaf(ag[2] * w2, r, fmaf(bd[2], un, ab[2]));
        z3 = fmaf(ag[3] * w3, r, fmaf(bd[3], un, ab[3]));
      }
      atomicExch(&srow[(chn << 6) + lane], stk);      // publish s chunk
      asm volatile("s_waitcnt vmcnt(0)" ::: "memory");// s at coherent point
      if (lane == 0) atomicExch(&sflag[b << 5], chn + 1);  // per-b progress
      uch = uch_next;
    }
  }
}

extern "C" void kernel_launch(void* const* d_in, const int* in_sizes, int n_in,
                              void* d_out, int out_size, void* d_ws, size_t ws_size,
                              hipStream_t stream) {
  const float* x     = (const float*)d_in[0];
  const float* llr   = (const float*)d_in[1];
  const float* logb  = (const float*)d_in[2];
  const float* c     = (const float*)d_in[3];
  const float* logd  = (const float*)d_in[4];
  const float* lstep = (const float*)d_in[5];
  const float* alpha = (const float*)d_in[6];
  const float* gma   = (const float*)d_in[7];
  const float* bta   = (const float*)d_in[8];

  float* u     = (float*)d_ws;            // B*S floats
  float* s     = u + B * S;               // B*S floats
  int*   uflag = (int*)(s + B * S);       // B*32 ints: one 128B line per batch
  int*   sflag = uflag + B * 32;          // B*32 ints: one 128B line per batch

  hipMemsetAsync(uflag, 0, 2 * B * 32 * sizeof(int), stream);
  fused<<<SBLK + WBLK, 512, 0, stream>>>(
      (const float4*)x, llr, logb, c, lstep, gma, bta, logd, alpha,
      u, s, uflag, sflag, (float4*)d_out);
}

// Round 4
// 630.137 us; speedup vs baseline: 4.7734x; 1.2337x over previous
//
#include <hip/hip_runtime.h>

// Problem constants (fixed by the reference)
constexpr int B = 32, S = 2048, D = 1024, N = 256;
constexpr int NCHUNK = 32;     // S/64 chunks
constexpr int SBLK   = 32;     // scan blocks (first; wave 0 only -> own CU/SIMD)
constexpr int WBLK   = 128;    // worker blocks: 16 waves x 1 row/wave
// Dispatch 2 grid = 160 blocks <= 256 CUs: every block gets its own CU.
// Deadlock-free BY CONSTRUCTION: scan waits on nothing (u is ready from
// dispatch 1); workers wait only on scan's monotone per-batch progress flag.

#define DEV __device__ __forceinline__

// ---- DPP wave-64 reduction helpers -------------------------------------
template <int CTRL>
DEV float dpp_add(float x) {
  int y = __builtin_amdgcn_update_dpp(0, __float_as_int(x), CTRL, 0xF, 0xF, true);
  return x + __int_as_float(y);
}

DEV float rdlane(float v, int l) {
  return __int_as_float(__builtin_amdgcn_readlane(__float_as_int(v), l));
}

DEV void wave_reduce3(float& a, float& b, float& c) {
  a = dpp_add<0x111>(a); b = dpp_add<0x111>(b); c = dpp_add<0x111>(c);
  a = dpp_add<0x112>(a); b = dpp_add<0x112>(b); c = dpp_add<0x112>(c);
  a = dpp_add<0x114>(a); b = dpp_add<0x114>(b); c = dpp_add<0x114>(c);
  a = dpp_add<0x118>(a); b = dpp_add<0x118>(b); c = dpp_add<0x118>(c);
  a = dpp_add<0x142>(a); b = dpp_add<0x142>(b); c = dpp_add<0x142>(c);
  a = dpp_add<0x143>(a); b = dpp_add<0x143>(b); c = dpp_add<0x143>(c);
  a = rdlane(a, 63);
  b = rdlane(b, 63);
  c = rdlane(c, 63);
}

// ---- cross-block communication primitives (verified discipline) ---------
// Producer: atomicExch data (device-scope RMW -> coherent point), vmcnt(0)
// drain, then flag RMW. Consumer: relaxed agent-scope atomic loads (bypass).
DEV float ld_agent(const float* p) {
  return __hip_atomic_load(p, __ATOMIC_RELAXED, __HIP_MEMORY_SCOPE_AGENT);
}
DEV int ld_flag(const int* p) {
  return __hip_atomic_load(p, __ATOMIC_RELAXED, __HIP_MEMORY_SCOPE_AGENT);
}

// ---- Dispatch 1: u[b,s] = mean_d x[b,s,d] (baseline-proven, full grid) --
__global__ __launch_bounds__(256) void mean_kernel(const float4* __restrict__ x4,
                                                   float* __restrict__ u) {
  const int row  = (blockIdx.x << 2) | (threadIdx.x >> 6);
  const int lane = threadIdx.x & 63;
  const float4* xr = x4 + (size_t)row * (D / 4);
  float s = 0.f;
#pragma unroll
  for (int j = 0; j < 4; ++j) {
    float4 v = xr[lane + (j << 6)];
    s += (v.x + v.y) + (v.z + v.w);
  }
#pragma unroll
  for (int off = 32; off; off >>= 1) s += __shfl_xor(s, off, 64);
  if (lane == 0) u[row] = s * (1.f / 1024.f);
}

// ---- Dispatch 2: fused scan + out-stream --------------------------------
// blocks [0, SBLK): scan, wave 0 only (batch = blockIdx). Plain cached u
//   loads; per-chunk publish of s + sflag[b*32] progress (the ONLY per-chunk
//   handshake in the design).
// blocks [SBLK, SBLK+WBLK): out workers; block = 16 rows of one batch,
//   1 row/wave. Per chunk: one scalar poller -> barrier -> stream 128 KB.
__global__ __launch_bounds__(1024) void fused(
    const float4* __restrict__ x4, const float* __restrict__ llr,
    const float* __restrict__ logb, const float* __restrict__ c,
    const float* __restrict__ lstep, const float* __restrict__ gma,
    const float* __restrict__ bta, const float* __restrict__ logd,
    const float* __restrict__ alpha, const float* __restrict__ u,
    float* __restrict__ s, int* __restrict__ sflag, float4* __restrict__ o4) {
  const int wv   = threadIdx.x >> 6;
  const int lane = threadIdx.x & 63;

  if (blockIdx.x >= SBLK) {
    // =================== OUT WORKER ===================
    const int wb = blockIdx.x - SBLK;            // 0..127
    const int b  = wb >> 2;                      // 4 blocks per batch
    const int i  = ((wb & 3) << 4) | wv;         // row-in-chunk 0..63
    const float asig = 1.f / (1.f + expf(-alpha[0]));
    const float dd   = expf(logd[0]);
    const float cx   = asig + (1.f - asig) * dd;
    const float cs   = 1.f - asig;
    for (int ch = 0; ch < NCHUNK; ++ch) {
      if (threadIdx.x == 0) {                    // ONE scalar poller per block
        while (ld_flag(&sflag[b << 5]) < ch + 1) __builtin_amdgcn_s_sleep(8);
      }
      __syncthreads();                           // all 16 waves gated on poll
      const int t = (ch << 6) | i;
      const float sv = cs * ld_agent(&s[b * S + t]);  // bypass; 1 txn (bcast)
      const float4* xr   = x4 + (size_t)(b * S + t) * (D / 4);
      float4*       orow = o4 + (size_t)(b * S + t) * (D / 4);
#pragma unroll
      for (int k = 0; k < 4; ++k) {
        float4 v = xr[lane + (k << 6)];
        float4 o;
        o.x = fmaf(cx, v.x, sv);
        o.y = fmaf(cx, v.y, sv);
        o.z = fmaf(cx, v.z, sv);
        o.w = fmaf(cx, v.w, sv);
        orow[lane + (k << 6)] = o;
      }
    }
  } else if (wv == 0) {
    // =================== SCAN (math identical to 690us baseline) ==========
    const int b = blockIdx.x;                    // batch 0..31, own CU/SIMD
    __builtin_amdgcn_s_setprio(1);               // bias issue arbitration
    const float stp = expf(lstep[0]);

    float ag[4], ab[4], bd[4], cg[4];
    float Gp = 0.f, BCp = 0.f, d0 = 0.f;
#pragma unroll
    for (int k = 0; k < 4; ++k) {
      const int n = (k << 6) | lane;
      const float lam = -expf(llr[n]);
      const float sl  = stp * lam;
      const float adisc = (2.f + sl) / (2.f - sl);
      const float bdisc = stp * (1.f + adisc) * expf(logb[n]) * 0.5f;
      const float g  = gma[n];
      const float be = bta[n];
      const float cc = c[n];
      ag[k] = adisc * g;
      ab[k] = adisc * be;
      bd[k] = bdisc;
      cg[k] = cc * g;
      Gp  += cg[k];
      BCp += cc * be;
    }
    wave_reduce3(Gp, BCp, d0);
    const float G = Gp, BC = BCp;
    const float Ceps = 65536.f * 1e-5f;

    const float* urow = u + b * S;               // ready: prior dispatch
    float* srow = s + b * S;

    float uch = urow[lane];                      // plain cached load
    const float u0 = rdlane(uch, 0);
    float z0 = bd[0] * u0, z1 = bd[1] * u0, z2 = bd[2] * u0, z3 = bd[3] * u0;

    for (int t0 = 0; t0 < S; t0 += 64) {
      int nx = t0 + 64 + lane;
      if (nx > S - 1) nx = S - 1;                // clamped prefetch (tail unused)
      const float uch_next = urow[nx];
      float stk = 0.f;
#pragma unroll
      for (int tt = 0; tt < 64; ++tt) {
        float s1 = (z0 + z1) + (z2 + z3);
        float s2 = fmaf(z0, z0, z1 * z1) + fmaf(z2, z2, z3 * z3);
        float s3 = fmaf(z0, cg[0], z1 * cg[1]) + fmaf(z2, cg[2], z3 * cg[3]);
        wave_reduce3(s1, s2, s3);
        const float q = fmaf(256.f, s2, fmaf(-s1, s1, Ceps));
        const float r = __builtin_amdgcn_rsqf(q);     // v_rsq_f32
        const float st = fmaf(r, fmaf(256.f, s3, -s1 * G), BC);
        stk = (lane == tt) ? st : stk;

        const float un = (tt < 63) ? rdlane(uch, tt + 1) : rdlane(uch_next, 0);
        const float w0 = fmaf(256.f, z0, -s1);
        const float w1 = fmaf(256.f, z1, -s1);
        const float w2 = fmaf(256.f, z2, -s1);
        const float w3 = fmaf(256.f, z3, -s1);
        z0 = fmaf(ag[0] * w0, r, fmaf(bd[0], un, ab[0]));
        z1 = fmaf(ag[1] * w1, r, fmaf(bd[1], un, ab[1]));
        z2 = fmaf(ag[2] * w2, r, fmaf(bd[2], un, ab[2]));
        z3 = fmaf(ag[3] * w3, r, fmaf(bd[3], un, ab[3]));
      }
      atomicExch(&srow[t0 + lane], stk);              // publish s chunk
      asm volatile("s_waitcnt vmcnt(0)" ::: "memory");// s at coherent point
      if (lane == 0) atomicExch(&sflag[b << 5], (t0 >> 6) + 1);
      uch = uch_next;
    }
  }
}

extern "C" void kernel_launch(void* const* d_in, const int* in_sizes, int n_in,
                              void* d_out, int out_size, void* d_ws, size_t ws_size,
                              hipStream_t stream) {
  const float* x     = (const float*)d_in[0];
  const float* llr   = (const float*)d_in[1];
  const float* logb  = (const float*)d_in[2];
  const float* c     = (const float*)d_in[3];
  const float* logd  = (const float*)d_in[4];
  const float* lstep = (const float*)d_in[5];
  const float* alpha = (const float*)d_in[6];
  const float* gma   = (const float*)d_in[7];
  const float* bta   = (const float*)d_in[8];

  float* u     = (float*)d_ws;            // B*S floats
  float* s     = u + B * S;               // B*S floats
  int*   sflag = (int*)(s + B * S);       // B*32 ints: one 128B line per batch

  hipMemsetAsync(sflag, 0, B * 32 * sizeof(int), stream);
  mean_kernel<<<B * S / 4, 256, 0, stream>>>((const float4*)x, u);
  fused<<<SBLK + WBLK, 1024, 0, stream>>>(
      (const float4*)x, llr, logb, c, lstep, gma, bta, logd, alpha,
      u, s, sflag, (float4*)d_out);
}

// Round 5
// 599.605 us; speedup vs baseline: 5.0165x; 1.0509x over previous
//
#include <hip/hip_runtime.h>

// Problem constants (fixed by the reference)
constexpr int B = 32, S = 2048, D = 1024, N = 256;
constexpr int NCHUNK = 32;     // S/64 chunks
constexpr int SBLK   = 32;     // scan blocks (first), wave 0 only
constexpr int WBLK   = 128;    // worker blocks: 16 waves x 1 row/wave
// Grid = 160 blocks x 1024 thr = 2560 waves << 8192 capacity: all resident.
// Deadlock-free: workers' mean phase waits on nothing -> uflag always
// advances -> scan advances -> sflag advances -> out phase advances.

#define DEV __device__ __forceinline__

// ---- DPP wave-64 reduction helpers -------------------------------------
template <int CTRL>
DEV float dpp_add(float x) {
  int y = __builtin_amdgcn_update_dpp(0, __float_as_int(x), CTRL, 0xF, 0xF, true);
  return x + __int_as_float(y);
}

DEV float rdlane(float v, int l) {
  return __int_as_float(__builtin_amdgcn_readlane(__float_as_int(v), l));
}

DEV void wave_reduce3(float& a, float& b, float& c) {
  a = dpp_add<0x111>(a); b = dpp_add<0x111>(b); c = dpp_add<0x111>(c);
  a = dpp_add<0x112>(a); b = dpp_add<0x112>(b); c = dpp_add<0x112>(c);
  a = dpp_add<0x114>(a); b = dpp_add<0x114>(b); c = dpp_add<0x114>(c);
  a = dpp_add<0x118>(a); b = dpp_add<0x118>(b); c = dpp_add<0x118>(c);
  a = dpp_add<0x142>(a); b = dpp_add<0x142>(b); c = dpp_add<0x142>(c);
  a = dpp_add<0x143>(a); b = dpp_add<0x143>(b); c = dpp_add<0x143>(c);
  a = rdlane(a, 63);
  b = rdlane(b, 63);
  c = rdlane(c, 63);
}

// ---- cross-block communication primitives (round-3/4 verified) ----------
// Producer: atomicExch data (device-scope RMW -> coherent point), vmcnt(0)
// drain, then flag RMW. Consumer: relaxed agent-scope atomic loads (bypass).
DEV float ld_agent(const float* p) {
  return __hip_atomic_load(p, __ATOMIC_RELAXED, __HIP_MEMORY_SCOPE_AGENT);
}
DEV int ld_flag(const int* p) {
  return __hip_atomic_load(p, __ATOMIC_RELAXED, __HIP_MEMORY_SCOPE_AGENT);
}

// ---- single fused kernel: mean -> scan -> out, chunk-pipelined ----------
// blocks [0, SBLK): scan, wave 0 only (batch = blockIdx).
// blocks [SBLK, SBLK+WBLK): workers; block = 16 rows (1/wave) of batch
//   b = wb/4.  Phase 1: mean of its rows across all 32 chunks (chunk-major,
//   NO waits), signaling uflag[b][q] once per 8-chunk QUARTER (ready at 4).
//   Phase 2: out-stream chunk ch once sflag[b] >= ch+1.
// Scan waits on uflag quarters (only q=0 is a real wait, ~13us); publishes
//   s per chunk with a DEFERRED flag: drain for chunk n-1 happens after
//   chunk n's 64 steps (6.6us later -> zero stall on the latency chain).
__global__ __launch_bounds__(1024) void fused(
    const float4* __restrict__ x4, const float* __restrict__ llr,
    const float* __restrict__ logb, const float* __restrict__ c,
    const float* __restrict__ lstep, const float* __restrict__ gma,
    const float* __restrict__ bta, const float* __restrict__ logd,
    const float* __restrict__ alpha, float* __restrict__ u,
    float* __restrict__ s, int* __restrict__ uflag, int* __restrict__ sflag,
    float4* __restrict__ o4) {
  const int wv   = threadIdx.x >> 6;
  const int lane = threadIdx.x & 63;

  if (blockIdx.x >= SBLK) {
    // =================== WORKER ===================
    const int wb = blockIdx.x - SBLK;            // 0..127
    const int b  = wb >> 2;                      // 4 blocks per batch
    const int i  = ((wb & 3) << 4) | wv;         // row-in-chunk 0..63

    // ---- phase 1: mean (wait-free; quarter-granularity signaling) ----
    for (int ch = 0; ch < NCHUNK; ++ch) {
      const int t = (ch << 6) | i;
      const float4* xr = x4 + (size_t)(b * S + t) * (D / 4);
      float sm = 0.f;
#pragma unroll
      for (int k = 0; k < 4; ++k) {
        float4 v = xr[lane + (k << 6)];
        sm += (v.x + v.y) + (v.z + v.w);
      }
#pragma unroll
      for (int off = 32; off; off >>= 1) sm += __shfl_xor(sm, off, 64);
      if (lane == 0) atomicExch(&u[b * S + t], sm * (1.f / 1024.f));
      if ((ch & 7) == 7) {                       // quarter boundary
        asm volatile("s_waitcnt vmcnt(0)" ::: "memory");  // u at coherent pt
        __syncthreads();                         // all 16 rows of block done
        if (threadIdx.x == 0) atomicAdd(&uflag[(b << 5) + (ch >> 3)], 1);
      }
    }

    // ---- phase 2: out, trailing the scan chunk-by-chunk ----
    const float asig = 1.f / (1.f + expf(-alpha[0]));
    const float dd   = expf(logd[0]);
    const float cx   = asig + (1.f - asig) * dd;
    const float cs   = 1.f - asig;
    for (int ch = 0; ch < NCHUNK; ++ch) {
      if (threadIdx.x == 0) {                    // ONE scalar poller per block
        while (ld_flag(&sflag[b << 5]) < ch + 1) __builtin_amdgcn_s_sleep(8);
      }
      __syncthreads();                           // all 16 waves gated on poll
      const int t = (ch << 6) | i;
      const float sv = cs * ld_agent(&s[b * S + t]);  // bypass; 1 txn (bcast)
      const float4* xr   = x4 + (size_t)(b * S + t) * (D / 4);
      float4*       orow = o4 + (size_t)(b * S + t) * (D / 4);
#pragma unroll
      for (int k = 0; k < 4; ++k) {
        float4 v = xr[lane + (k << 6)];
        float4 o;
        o.x = fmaf(cx, v.x, sv);
        o.y = fmaf(cx, v.y, sv);
        o.z = fmaf(cx, v.z, sv);
        o.w = fmaf(cx, v.w, sv);
        orow[lane + (k << 6)] = o;
      }
    }
  } else if (wv == 0) {
    // =================== SCAN (math identical to 690us baseline) ==========
    const int b = blockIdx.x;                    // batch 0..31
    __builtin_amdgcn_s_setprio(1);               // bias issue arbitration
    const float stp = expf(lstep[0]);

    float ag[4], ab[4], bd[4], cg[4];
    float Gp = 0.f, BCp = 0.f, d0 = 0.f;
#pragma unroll
    for (int k = 0; k < 4; ++k) {
      const int n = (k << 6) | lane;
      const float lam = -expf(llr[n]);
      const float sl  = stp * lam;
      const float adisc = (2.f + sl) / (2.f - sl);
      const float bdisc = stp * (1.f + adisc) * expf(logb[n]) * 0.5f;
      const float g  = gma[n];
      const float be = bta[n];
      const float cc = c[n];
      ag[k] = adisc * g;
      ab[k] = adisc * be;
      bd[k] = bdisc;
      cg[k] = cc * g;
      Gp  += cg[k];
      BCp += cc * be;
    }
    wave_reduce3(Gp, BCp, d0);
    const float G = Gp, BC = BCp;
    const float Ceps = 65536.f * 1e-5f;

    const float* urow = u + b * S;
    float* srow = s + b * S;

    // wait for quarter 0 of u (the only real wait, ~13us)
    while (ld_flag(&uflag[b << 5]) < 4) __builtin_amdgcn_s_sleep(2);
    __threadfence();
    float uch = ld_agent(urow + lane);           // chunk 0 of u (bypass)
    const float u0 = rdlane(uch, 0);
    float z0 = bd[0] * u0, z1 = bd[1] * u0, z2 = bd[2] * u0, z3 = bd[3] * u0;

    for (int chn = 0; chn < NCHUNK; ++chn) {
      float uch_next = uch;             // chunk 31: value only feeds dead state
      if (chn < NCHUNK - 1) {
        if (((chn + 1) & 7) == 0) {     // next quarter (workers far ahead)
          while (ld_flag(&uflag[(b << 5) + ((chn + 1) >> 3)]) < 4)
            __builtin_amdgcn_s_sleep(2);
          __threadfence();
        }
        uch_next = ld_agent(urow + ((chn + 1) << 6) + lane);  // prefetch
      }
      float stk = 0.f;
#pragma unroll
      for (int tt = 0; tt < 64; ++tt) {
        float s1 = (z0 + z1) + (z2 + z3);
        float s2 = fmaf(z0, z0, z1 * z1) + fmaf(z2, z2, z3 * z3);
        float s3 = fmaf(z0, cg[0], z1 * cg[1]) + fmaf(z2, cg[2], z3 * cg[3]);
        wave_reduce3(s1, s2, s3);
        const float q = fmaf(256.f, s2, fmaf(-s1, s1, Ceps));
        const float r = __builtin_amdgcn_rsqf(q);     // v_rsq_f32
        const float st = fmaf(r, fmaf(256.f, s3, -s1 * G), BC);
        stk = (lane == tt) ? st : stk;

        const float un = (tt < 63) ? rdlane(uch, tt + 1) : rdlane(uch_next, 0);
        const float w0 = fmaf(256.f, z0, -s1);
        const float w1 = fmaf(256.f, z1, -s1);
        const float w2 = fmaf(256.f, z2, -s1);
        const float w3 = fmaf(256.f, z3, -s1);
        z0 = fmaf(ag[0] * w0, r, fmaf(bd[0], un, ab[0]));
        z1 = fmaf(ag[1] * w1, r, fmaf(bd[1], un, ab[1]));
        z2 = fmaf(ag[2] * w2, r, fmaf(bd[2], un, ab[2]));
        z3 = fmaf(ag[3] * w3, r, fmaf(bd[3], un, ab[3]));
      }
      // Deferred publish: drain retires chunk chn-1's exch (issued 64 steps
      // ago -> instant), flag chn-1 ready, then issue chunk chn's exch.
      asm volatile("s_waitcnt vmcnt(0)" ::: "memory");
      if (lane == 0) atomicExch(&sflag[b << 5], chn);   // chunks < chn ready
      atomicExch(&srow[(chn << 6) + lane], stk);        // publish s chunk chn
      uch = uch_next;
    }
    asm volatile("s_waitcnt vmcnt(0)" ::: "memory");    // retire chunk 31
    if (lane == 0) atomicExch(&sflag[b << 5], NCHUNK);  // all chunks ready
  }
}

extern "C" void kernel_launch(void* const* d_in, const int* in_sizes, int n_in,
                              void* d_out, int out_size, void* d_ws, size_t ws_size,
                              hipStream_t stream) {
  const float* x     = (const float*)d_in[0];
  const float* llr   = (const float*)d_in[1];
  const float* logb  = (const float*)d_in[2];
  const float* c     = (const float*)d_in[3];
  const float* logd  = (const float*)d_in[4];
  const float* lstep = (const float*)d_in[5];
  const float* alpha = (const float*)d_in[6];
  const float* gma   = (const float*)d_in[7];
  const float* bta   = (const float*)d_in[8];

  float* u     = (float*)d_ws;            // B*S floats
  float* s     = u + B * S;               // B*S floats
  int*   uflag = (int*)(s + B * S);       // B*32 ints: one 128B line per batch
  int*   sflag = uflag + B * 32;          // B*32 ints: one 128B line per batch

  hipMemsetAsync(uflag, 0, 2 * B * 32 * sizeof(int), stream);
  fused<<<SBLK + WBLK, 1024, 0, stream>>>(
      (const float4*)x, llr, logb, c, lstep, gma, bta, logd, alpha,
      u, s, uflag, sflag, (float4*)d_out);
}